// Round 11
// baseline (128.813 us; speedup 1.0000x reference)
//
#include <hip/hip_runtime.h>
#include <math.h>

// Problem constants (B,C,H,W = 16,64,256,256; RATIO=2, GROUPS=4)
#define BATCH 16
#define CIN   64
#define HIN   256
#define WIN   256
#define HOUT  128
#define WOUT  128
#define NPIX  (HIN * WIN)          // 65536
#define NPIXO (HOUT * WOUT)        // 16384
#define OUT0_SIZE ((size_t)BATCH * CIN * NPIXO)   // 16777216

#define NTILE 16                   // 8x8-output tiles per dim (128/8)
#define NPAIR 136                  // NTILE*(NTILE+1)/2 pair-units per batch
#define SQ_CH 256                  // shorts per channel plane (16x16, pitch 16)
#define SQ_SZ (64 * SQ_CH)         // shorts per square (64 ch)

typedef __attribute__((ext_vector_type(4))) float f32x4;

__device__ __forceinline__ unsigned short f2bf(float f) {   // RNE f32->bf16
    unsigned u = __float_as_uint(f);
    return (unsigned short)((u + 0x7FFFu + ((u >> 16) & 1u)) >> 16);
}

// ---------------------------------------------------------------------------
// v5: tile-PAIR blocks with full LDS retention (kills the 268MB gather
// re-read over the XCD fabric).
//
// Key identity: gather region of 8x8 output tile (p,q) == 16x16 input conv
// square of tile (q,p) (the op transposes coordinates). A block owns the
// pair {(p,q),(q,p)} (diagonal: single tile), stages both squares x 64ch
// ONCE into LDS as bf16 (64KB), computes conv offsets FROM LDS, samples
// FROM LDS. Global-memory fallback (exact f32) behind a wave-uniform
// __all predicate covers offset outliers / image borders.
// Output transpose done with one __shfl lane permutation per sample.
// LDS ~70KB -> 2 blocks/CU so staging of one block overlaps compute of the
// other. Fabric bytes: 268MB x-read (once) + 84MB writes = 352MB floor.
// ---------------------------------------------------------------------------
__global__ __launch_bounds__(256, 2) void k_fused(
    const float* __restrict__ x,
    const float* __restrict__ w_off, const float* __restrict__ b_off,
    const float* __restrict__ w_sc,  const float* __restrict__ b_sc,
    float* __restrict__ out, float* __restrict__ offg)
{
    __shared__ unsigned short sq[2 * SQ_SZ];   // 64 KiB: 2 squares, bf16
    __shared__ float soff[2][4][8][8][2];      // 4 KiB: [tile][grp][hl][wl][two]
    __shared__ float sw[256];                  // 1 KiB: conv weights

    const int t = threadIdx.x;
    sw[t] = (t < 128) ? w_off[t] : w_sc[t - 128];

    // ---- block -> (b, p<=q) triangular decode ----
    int blk = blockIdx.x;
    int b = blk / NPAIR;
    int u = blk - b * NPAIR;
    int p = 0;
    while (u >= NTILE - p) { u -= NTILE - p; ++p; }
    const int q = p + u;
    const bool diag = (p == q);
    const int nsq = diag ? 1 : 2;

    const float* xb = x + (size_t)b * CIN * NPIX;
    // sq0 = square(p,q): rows 16p, cols 16q (conv region of tile A=(p,q))
    // sq1 = square(q,p): rows 16q, cols 16p (conv region of tile B=(q,p))
    const int rb[2] = {16 * p, 16 * q};
    const int cb[2] = {16 * q, 16 * p};

    // ---- stage both squares, all 64 ch, f32 global -> bf16 LDS ----
    // idx = (sq, ch, row, q4): 4 lanes cover one 64B row; coalesced.
    for (int it = 0; it < 16 * nsq; ++it) {
        int idx = it * 256 + t;
        int s   = idx >> 12;
        int rem = idx & 4095;
        int ch  = rem >> 6;
        int row = (rem >> 2) & 15;
        int q4  = rem & 3;
        const float* gp = xb + (size_t)ch * NPIX
                        + (size_t)(rb[s] + row) * WIN + cb[s] + q4 * 4;
        f32x4 f = *reinterpret_cast<const f32x4*>(gp);
        ushort4 h;
        h.x = f2bf(f[0]); h.y = f2bf(f[1]); h.z = f2bf(f[2]); h.w = f2bf(f[3]);
        *reinterpret_cast<ushort4*>(
            &sq[s * SQ_SZ + ch * SQ_CH + row * 16 + q4 * 4]) = h;
    }
    __syncthreads();

    // ---- conv offsets from LDS (one conv pixel per thread per square) ----
    const float bo0 = b_off[0], bo1 = b_off[1];
    const float bs0 = b_sc[0],  bs1 = b_sc[1];
    for (int s = 0; s < nsq; ++s) {
        const int r = t >> 4, c = t & 15;
        const unsigned short* sp = &sq[s * SQ_SZ + r * 16 + c];
        float a0 = 0, a1 = 0, z0 = 0, z1 = 0;
        #pragma unroll 16
        for (int ch = 0; ch < 64; ++ch) {
            float xv = __uint_as_float((unsigned)sp[ch * SQ_CH] << 16);
            a0 += xv * sw[ch];       a1 += xv * sw[64 + ch];
            z0 += xv * sw[128 + ch]; z1 += xv * sw[192 + ch];
        }
        float o0 = 0.5f * (a0 + bo0) / (1.0f + __expf(-(z0 + bs0)));
        float o1 = 0.5f * (a1 + bo1) / (1.0f + __expf(-(z1 + bs1)));
        // conv px (r,c) -> output px (hl,wl), parity (i,j): grp = 2o+i, two = j
        const int i = r & 1, j = c & 1, hl = r >> 1, wl = c >> 1;
        soff[s][i][hl][wl][j]     = o0;
        soff[s][2 + i][hl][wl][j] = o1;
        const int hh = (s ? 8 * q : 8 * p) + hl;
        const int ww = (s ? 8 * p : 8 * q) + wl;
        size_t o0i = (((size_t)(b * 4 + i))     * HOUT + hh) * WOUT + ww;
        size_t o1i = (((size_t)(b * 4 + 2 + i)) * HOUT + hh) * WOUT + ww;
        __builtin_nontemporal_store(o0, offg + 2 * o0i + j);
        __builtin_nontemporal_store(o1, offg + 2 * o1i + j);
    }
    __syncthreads();

    // ---- bilinear sampling from LDS ----
    // wave = (tile, ch-half): lane -> px (hl = lane&7 drives COLUMN coord,
    // wl = lane>>3 drives ROW coord — the op transposes coordinates).
    const int lane = t & 63;
    const int half = (t >> 6) & 1;
    const int tile = t >> 7;
    if (!(diag && tile == 1)) {
        const int hl = lane & 7, wl = lane >> 3;
        const int hb = tile ? 8 * q : 8 * p;
        const int wb = tile ? 8 * p : 8 * q;
        const int gs = diag ? 0 : (1 - tile);    // gather square index
        const int RB = rb[gs], CB = cb[gs];
        const int hh = hb + hl, ww = wb + wl;
        // transpose: store-lane L takes value from lane ((L&7)<<3)|(L>>3)
        const int srcl = ((lane & 7) << 3) | (lane >> 3);
        const int hh2 = hb + (lane >> 3), ww2 = wb + (lane & 7);
        float* outp = out + (size_t)b * CIN * NPIXO
                    + (size_t)hh2 * WOUT + ww2;

        #pragma unroll
        for (int g = 0; g < 4; ++g) {
            const float ox = soff[tile][g][hl][wl][0];
            const float oy = soff[tile][g][hl][wl][1];
            float ix = 2.0f * (float)hh + 0.5f + 2.0f * ox;   // column coord
            float iy = 2.0f * (float)ww + 0.5f + 2.0f * oy;   // row coord
            ix = fminf(fmaxf(ix, 0.0f), 255.0f);
            iy = fminf(fmaxf(iy, 0.0f), 255.0f);
            float x0f = floorf(ix), y0f = floorf(iy);
            float wx = ix - x0f, wy = iy - y0f;
            int x0 = (int)x0f, y0 = (int)y0f;
            int x1 = min(x0 + 1, WIN - 1);
            int y1 = min(y0 + 1, HIN - 1);
            float w00 = (1.0f - wx) * (1.0f - wy);
            float w01 = wx * (1.0f - wy);
            float w10 = (1.0f - wx) * wy;
            float w11 = wx * wy;

            const int xl = x0 - CB, yl = y0 - RB;
            bool ok = (xl >= 0) & (xl <= 14) & ((xl & 1) == 0)
                    & (yl >= 0) & (yl <= 14)
                    & (x1 == x0 + 1) & (y1 == y0 + 1);

            if (__all(ok)) {
                // fast path: 2x2 footprint inside the staged square
                const unsigned short* spg = &sq[gs * SQ_SZ + yl * 16 + xl];
                #pragma unroll
                for (int ci = 0; ci < 8; ++ci) {
                    const int ch = 4 * (half * 8 + ci) + g;
                    const unsigned short* cp = spg + ch * SQ_CH;
                    unsigned v0 = *reinterpret_cast<const unsigned*>(cp);
                    unsigned v1 = *reinterpret_cast<const unsigned*>(cp + 16);
                    float f00 = __uint_as_float(v0 << 16);
                    float f01 = __uint_as_float(v0 & 0xFFFF0000u);
                    float f10 = __uint_as_float(v1 << 16);
                    float f11 = __uint_as_float(v1 & 0xFFFF0000u);
                    float v = f00 * w00 + f01 * w01 + f10 * w10 + f11 * w11;
                    float vt = __shfl(v, srcl, 64);
                    __builtin_nontemporal_store(vt, outp + (size_t)ch * NPIXO);
                }
            } else {
                // exact f32 global fallback (borders / large offsets)
                int i00 = y0 * WIN + x0, i01 = y0 * WIN + x1;
                int i10 = y1 * WIN + x0, i11 = y1 * WIN + x1;
                #pragma unroll
                for (int ci = 0; ci < 8; ++ci) {
                    const int ch = 4 * (half * 8 + ci) + g;
                    const float* xc = xb + (size_t)ch * NPIX;
                    float v = xc[i00] * w00 + xc[i01] * w01
                            + xc[i10] * w10 + xc[i11] * w11;
                    float vt = __shfl(v, srcl, 64);
                    __builtin_nontemporal_store(vt, outp + (size_t)ch * NPIXO);
                }
            }
        }
    }
}

extern "C" void kernel_launch(void* const* d_in, const int* in_sizes, int n_in,
                              void* d_out, int out_size, void* d_ws, size_t ws_size,
                              hipStream_t stream) {
    const float* x     = (const float*)d_in[0];
    const float* w_off = (const float*)d_in[1];
    const float* b_off = (const float*)d_in[2];
    const float* w_sc  = (const float*)d_in[3];
    const float* b_sc  = (const float*)d_in[4];

    float* out  = (float*)d_out;
    float* offg = out + OUT0_SIZE;   // second return value, concatenated

    // 16 batches x 136 tile-pair units = 2176 blocks, 256 threads, 2/CU
    k_fused<<<BATCH * NPAIR, 256, 0, stream>>>(
        x, w_off, b_off, w_sc, b_sc, out, offg);
}

// Round 12
// 125.075 us; speedup vs baseline: 1.0299x; 1.0299x over previous
//
#include <hip/hip_runtime.h>
#include <math.h>

// Problem constants (B,C,H,W = 16,64,256,256; RATIO=2, GROUPS=4)
#define BATCH 16
#define CIN   64
#define HIN   256
#define WIN   256
#define HOUT  128
#define WOUT  128
#define NPIX  (HIN * WIN)          // 65536
#define NPIXO (HOUT * WOUT)        // 16384
#define OUT0_SIZE ((size_t)BATCH * CIN * NPIXO)   // 16777216

#define NTILE 16                   // 8x8-output tiles per dim
#define NPAIR 136                  // triangular pairs per batch
#define NUNITS (BATCH * NPAIR)     // 2176
#define NBLK  256                  // persistent blocks (1 per CU)
#define PITCH 18                   // floats per LDS row (even -> 8B align)
#define PLANE (16 * PITCH)         // 288 floats per channel plane

typedef __attribute__((ext_vector_type(4))) float f32x4;

__device__ __forceinline__ void decode_pair(int U, int& b, int& p, int& q) {
    b = U / NPAIR;
    int u = U - b * NPAIR;
    int pp = 0;
    while (u >= NTILE - pp) { u -= NTILE - pp; ++pp; }
    p = pp; q = pp + u;
}

// ---------------------------------------------------------------------------
// v7: persistent pair-retention pipeline.
// Pair {(p,q),(q,p)}: gather region of tile (p,q) == conv square of (q,p).
// Block stages both 16x16x64ch squares in f32 LDS (pitch 18, 147KB), does
// conv + sampling entirely from LDS (exact f32). Next pair's 128KB is
// issued into registers at loop top (T14 issue-early) and ds_written after
// the post-sampling barrier -> HBM read streams continuously under compute.
// Port-byte floor: 268MB x-read (once, 64B rows at 16-wave depth) + 84MB NT
// writes. 3 barriers/pair.
// ---------------------------------------------------------------------------
__global__ __launch_bounds__(1024, 1) void k_fused(
    const float* __restrict__ x,
    const float* __restrict__ w_off, const float* __restrict__ b_off,
    const float* __restrict__ w_sc,  const float* __restrict__ b_sc,
    float* __restrict__ out, float* __restrict__ offg)
{
    __shared__ float sq[2 * 64 * PLANE];      // 147456 B
    __shared__ float soff[2][4][8][8][2];     // 4096 B
    __shared__ float swt[256];                // 1024 B

    const int t = threadIdx.x;
    if (t < 256) swt[t] = (t < 128) ? w_off[t] : w_sc[t - 128];

    const int blk = blockIdx.x;
    // 2176 = 256*8 + 128 -> blocks 0-127 do 9 pairs, 128-255 do 8
    const int np = (blk < NUNITS - NBLK * 8) ? 9 : 8;

    const float bo0 = b_off[0], bo1 = b_off[1];
    const float bs0 = b_sc[0],  bs1 = b_sc[1];

    // staging decode for unit k*1024+t: s=k>>2, rem=((k&3)<<10)|t,
    // ch=rem>>6, row=(rem>>2)&15, qq=rem&3
    // ---- prologue: stage pair 0 directly ----
    {
        int b0, p0, q0; decode_pair(blk, b0, p0, q0);
        const bool d0 = (p0 == q0);
        const int rb[2] = {16 * p0, 16 * q0}, cb[2] = {16 * q0, 16 * p0};
        const float* xb0 = x + (size_t)b0 * CIN * NPIX;
        #pragma unroll
        for (int k = 0; k < 8; ++k) {
            const int s = k >> 2;
            if (s && d0) continue;
            const int rem = ((k & 3) << 10) | t;
            const int ch = rem >> 6, row = (rem >> 2) & 15, qq = rem & 3;
            f32x4 v = *reinterpret_cast<const f32x4*>(
                xb0 + (size_t)ch * NPIX + (size_t)(rb[s] + row) * WIN
                    + cb[s] + 4 * qq);
            float* d = &sq[(s * 64 + ch) * PLANE + row * PITCH + 4 * qq];
            *reinterpret_cast<float2*>(d)     = make_float2(v[0], v[1]);
            *reinterpret_cast<float2*>(d + 2) = make_float2(v[2], v[3]);
        }
    }
    __syncthreads();

    int U = blk;
    for (int it = 0; it < np; ++it) {
        int b, p, q; decode_pair(U, b, p, q);
        const bool diag = (p == q);
        const float* xb = x + (size_t)b * CIN * NPIX;

        // ---- issue next pair's loads (drain under conv+sampling) ----
        const bool hasNext = (it + 1 < np);
        f32x4 hold[8];
        bool diagn = false;
        if (hasNext) {
            int bn, pn, qn; decode_pair(U + NBLK, bn, pn, qn);
            diagn = (pn == qn);
            const int rbn[2] = {16 * pn, 16 * qn}, cbn[2] = {16 * qn, 16 * pn};
            const float* xbn = x + (size_t)bn * CIN * NPIX;
            #pragma unroll
            for (int k = 0; k < 8; ++k) {
                const int s = k >> 2;
                if (s && diagn) continue;
                const int rem = ((k & 3) << 10) | t;
                const int ch = rem >> 6, row = (rem >> 2) & 15, qq = rem & 3;
                hold[k] = *reinterpret_cast<const f32x4*>(
                    xbn + (size_t)ch * NPIX + (size_t)(rbn[s] + row) * WIN
                        + cbn[s] + 4 * qq);
            }
        }

        // ---- conv1x1 offsets from LDS (2 threads per conv pixel) ----
        const int nsq = diag ? 1 : 2;
        if (t < 512 * nsq) {
            const int s = t >> 9;
            const int pxh = t & 511;
            const int px = pxh >> 1, half = pxh & 1;
            const int r = px >> 4, c = px & 15;
            const float* base = &sq[(s * 64 + half * 32) * PLANE
                                    + r * PITCH + c];
            float a0 = 0, a1 = 0, z0 = 0, z1 = 0;
            #pragma unroll
            for (int cc = 0; cc < 32; ++cc) {
                const float xv = base[cc * PLANE];
                const int ch = half * 32 + cc;
                a0 += xv * swt[ch];        a1 += xv * swt[64 + ch];
                z0 += xv * swt[128 + ch];  z1 += xv * swt[192 + ch];
            }
            a0 += __shfl_xor(a0, 1);  a1 += __shfl_xor(a1, 1);
            z0 += __shfl_xor(z0, 1);  z1 += __shfl_xor(z1, 1);
            if (half == 0) {
                const float o0 = 0.5f * (a0 + bo0) / (1.0f + __expf(-(z0 + bs0)));
                const float o1 = 0.5f * (a1 + bo1) / (1.0f + __expf(-(z1 + bs1)));
                const int i = r & 1, j = c & 1, hl = r >> 1, wl = c >> 1;
                soff[s][i][hl][wl][j]     = o0;
                soff[s][2 + i][hl][wl][j] = o1;
                const int hh = (s ? 8 * q : 8 * p) + hl;
                const int ww = (s ? 8 * p : 8 * q) + wl;
                size_t o0i = (((size_t)(b * 4 + i))     * HOUT + hh) * WOUT + ww;
                size_t o1i = (((size_t)(b * 4 + 2 + i)) * HOUT + hh) * WOUT + ww;
                __builtin_nontemporal_store(o0, offg + 2 * o0i + j);
                __builtin_nontemporal_store(o1, offg + 2 * o1i + j);
            }
        }
        __syncthreads();   // B1: soff ready

        // ---- bilinear sampling from LDS ----
        {
            const int w = t >> 6, lane = t & 63;
            const int nsl = diag ? 16 : 8;
            const int T   = diag ? 0 : (w >> 3);
            const int sl  = diag ? w : (w & 7);
            const int ppw = 64 / nsl;          // planes per wave: 4 or 8
            const int hl = lane & 7, wl = lane >> 3;
            const int hb = T ? 8 * q : 8 * p;
            const int wb = T ? 8 * p : 8 * q;
            const int gs = diag ? 0 : (1 - T);         // gather square
            const int RB = gs ? 16 * q : 16 * p;
            const int CB = gs ? 16 * p : 16 * q;
            const int srcl = ((lane & 7) << 3) | (lane >> 3);
            float* outp = out + (size_t)b * CIN * NPIXO
                        + (size_t)(hb + (lane >> 3)) * WOUT + (wb + (lane & 7));
            const int hh = hb + hl, ww = wb + wl;

            for (int ci = 0; ci < ppw; ++ci) {
                const int c = sl * ppw + ci;   // actual channel = plane
                const int g = c & 3;           // its group
                const float ox = soff[T][g][hl][wl][0];
                const float oy = soff[T][g][hl][wl][1];
                // transposed coords: ix (column) from hh, iy (row) from ww
                float ix = 2.0f * (float)hh + 0.5f + 2.0f * ox;
                float iy = 2.0f * (float)ww + 0.5f + 2.0f * oy;
                ix = fminf(fmaxf(ix, 0.0f), 255.0f);
                iy = fminf(fmaxf(iy, 0.0f), 255.0f);
                const float x0f = floorf(ix), y0f = floorf(iy);
                const float wx = ix - x0f, wy = iy - y0f;
                const int x0 = (int)x0f, y0 = (int)y0f;
                const int x1 = min(x0 + 1, WIN - 1);
                const int y1 = min(y0 + 1, HIN - 1);
                const float w00 = (1.0f - wx) * (1.0f - wy);
                const float w01 = wx * (1.0f - wy);
                const float w10 = (1.0f - wx) * wy;
                const float w11 = wx * wy;
                const int xl = x0 - CB, yl = y0 - RB;
                const bool ok = (xl >= 0) & (xl <= 14) & ((xl & 1) == 0)
                              & (yl >= 0) & (yl <= 14)
                              & (x1 == x0 + 1) & (y1 == y0 + 1);
                float val;
                if (__all(ok)) {
                    const float* sp = &sq[(gs * 64 + c) * PLANE
                                          + yl * PITCH + xl];
                    const float2 v0 = *reinterpret_cast<const float2*>(sp);
                    const float2 v1 = *reinterpret_cast<const float2*>(sp + PITCH);
                    val = v0.x * w00 + v0.y * w01 + v1.x * w10 + v1.y * w11;
                } else {
                    const float* xc = xb + (size_t)c * NPIX;
                    const int i00 = y0 * WIN + x0, i01 = y0 * WIN + x1;
                    const int i10 = y1 * WIN + x0, i11 = y1 * WIN + x1;
                    val = xc[i00] * w00 + xc[i01] * w01
                        + xc[i10] * w10 + xc[i11] * w11;
                }
                const float vt = __shfl(val, srcl, 64);
                __builtin_nontemporal_store(vt, outp + (size_t)c * NPIXO);
            }
        }
        __syncthreads();   // B2: all sq reads done

        // ---- write staged next pair into LDS ----
        if (hasNext) {
            #pragma unroll
            for (int k = 0; k < 8; ++k) {
                const int s = k >> 2;
                if (s && diagn) continue;
                const int rem = ((k & 3) << 10) | t;
                const int ch = rem >> 6, row = (rem >> 2) & 15, qq = rem & 3;
                float* d = &sq[(s * 64 + ch) * PLANE + row * PITCH + 4 * qq];
                *reinterpret_cast<float2*>(d)     = make_float2(hold[k][0], hold[k][1]);
                *reinterpret_cast<float2*>(d + 2) = make_float2(hold[k][2], hold[k][3]);
            }
        }
        __syncthreads();   // B3: sq ready for next conv
        U += NBLK;
    }
}

extern "C" void kernel_launch(void* const* d_in, const int* in_sizes, int n_in,
                              void* d_out, int out_size, void* d_ws, size_t ws_size,
                              hipStream_t stream) {
    const float* x     = (const float*)d_in[0];
    const float* w_off = (const float*)d_in[1];
    const float* b_off = (const float*)d_in[2];
    const float* w_sc  = (const float*)d_in[3];
    const float* b_sc  = (const float*)d_in[4];

    float* out  = (float*)d_out;
    float* offg = out + OUT0_SIZE;   // second return value, concatenated

    // 256 persistent blocks (1/CU) x 1024 threads
    k_fused<<<NBLK, 1024, 0, stream>>>(x, w_off, b_off, w_sc, b_sc, out, offg);
}

// Round 13
// 92.623 us; speedup vs baseline: 1.3907x; 1.3504x over previous
//
#include <hip/hip_runtime.h>
#include <math.h>

// Problem constants (B,C,H,W = 16,64,256,256; RATIO=2, GROUPS=4)
#define BATCH 16
#define CIN   64
#define HIN   256
#define WIN   256
#define HOUT  128
#define WOUT  128
#define NPIX  (HIN * WIN)          // 65536
#define NPIXO (HOUT * WOUT)        // 16384
#define OUT0_SIZE ((size_t)BATCH * CIN * HOUT * WOUT)   // 16777216

// ---------------------------------------------------------------------------
// v8 = r7's 97.7us kernel body (unchanged) + XCD pair-locality swizzle.
//
// Identity: gather region of tile (th,tw) == conv square of partner (tw,th)
// (the op transposes coordinates). Default round-robin put partners on
// DIFFERENT XCDs (xcd=tw vs th), so phase-2 gathers crossed the fabric to
// L3. New decode co-locates each pair {(i,j),(j,i)} on one XCD at adjacent
// per-XCD dispatch slots, and gives XCD x exactly batches {2x, 2x+1}:
//   pos<112: off-diag pair v = xcd*56 + (pos>>1), side = pos&1
//   pos>=112: diagonal tiles (self-partnered)
// Phase-2 gathers then hit the XCD's own L2 instead of crossing to L3.
// ---------------------------------------------------------------------------
__global__ __launch_bounds__(256) void k_fused(
    const float* __restrict__ x,
    const float* __restrict__ w_off, const float* __restrict__ b_off,
    const float* __restrict__ w_sc,  const float* __restrict__ b_sc,
    float* __restrict__ out, float* __restrict__ offg)
{
    __shared__ float  sw[256];            // w_off ch0/ch1, w_sc ch0/ch1
    __shared__ float2 soff[4][16][17];    // [grp][row][col], padded
    __shared__ float  sval[16][272];      // [c][hl*17+wl], one group at a time

    int t = threadIdx.x;
    sw[t] = (t < 128) ? w_off[t] : w_sc[t - 128];

    // ---- XCD pair-locality decode ----
    int g_   = blockIdx.x;        // [0,1024)
    int xcd  = g_ & 7;
    int pos  = g_ >> 3;           // per-XCD slot [0,128)
    int b, th, tw;
    if (pos < 112) {
        int s = pos >> 1, side = pos & 1;
        int v = xcd * 56 + s;     // off-diagonal pair unit [0,448)
        b = v / 28;
        int pidx = v - b * 28;    // strict upper-triangle index [0,28)
        int i = 0;
        while (pidx >= 7 - i) { pidx -= 7 - i; ++i; }
        int j = i + 1 + pidx;
        th = side ? j : i;
        tw = side ? i : j;
    } else {
        int w_ = xcd * 16 + (pos - 112);   // diagonal unit [0,128)
        b = w_ >> 3;
        th = tw = w_ & 7;
    }
    int hh0 = th * 16, ww0 = tw * 16;

    // ---------------- phase 1: conv1x1 offsets ----------------
    int row = t >> 4, col = t & 15;       // ww-fast mapping
    int hh = hh0 + row, ww = ww0 + col;

    const float* xb = x + (size_t)b * CIN * NPIX + (2 * hh) * WIN + 2 * ww;

    float aA0[2][2] = {{0,0},{0,0}}, aA1[2][2] = {{0,0},{0,0}};
    float aS0[2][2] = {{0,0},{0,0}}, aS1[2][2] = {{0,0},{0,0}};

    __syncthreads();   // sw ready

    #pragma unroll 8
    for (int c = 0; c < CIN; ++c) {
        const float* xc = xb + (size_t)c * NPIX;
        float2 r0 = *reinterpret_cast<const float2*>(xc);        // row 2hh
        float2 r1 = *reinterpret_cast<const float2*>(xc + WIN);  // row 2hh+1
        float wo0 = sw[c], wo1 = sw[64 + c], ws0 = sw[128 + c], ws1 = sw[192 + c];
        aA0[0][0] += r0.x * wo0;  aA0[0][1] += r0.y * wo0;
        aA0[1][0] += r1.x * wo0;  aA0[1][1] += r1.y * wo0;
        aA1[0][0] += r0.x * wo1;  aA1[0][1] += r0.y * wo1;
        aA1[1][0] += r1.x * wo1;  aA1[1][1] += r1.y * wo1;
        aS0[0][0] += r0.x * ws0;  aS0[0][1] += r0.y * ws0;
        aS0[1][0] += r1.x * ws0;  aS0[1][1] += r1.y * ws0;
        aS1[0][0] += r0.x * ws1;  aS1[0][1] += r0.y * ws1;
        aS1[1][0] += r1.x * ws1;  aS1[1][1] += r1.y * ws1;
    }

    float bo0 = b_off[0], bo1 = b_off[1];
    float bs0 = b_sc[0],  bs1 = b_sc[1];

    // offg[grp][two]: grp = 2*o + i (conv row parity), two = j (col parity)
    float og[4][2];
    #pragma unroll
    for (int i = 0; i < 2; ++i) {
        #pragma unroll
        for (int j = 0; j < 2; ++j) {
            float g0 = 1.0f / (1.0f + __expf(-(aS0[i][j] + bs0)));
            float g1 = 1.0f / (1.0f + __expf(-(aS1[i][j] + bs1)));
            og[i][j]     = g0 * 0.5f * (aA0[i][j] + bo0);
            og[2 + i][j] = g1 * 0.5f * (aA1[i][j] + bo1);
        }
    }

    #pragma unroll
    for (int g = 0; g < 4; ++g) {
        float2 vv = make_float2(og[g][0], og[g][1]);
        soff[g][row][col] = vv;
        size_t oi = ((size_t)((b * 4 + g) * HOUT + hh)) * WOUT + ww;
        // nontemporal 8B store: offg is write-only output, keep it out of cache
        __builtin_nontemporal_store(__builtin_bit_cast(double, vv),
                                    reinterpret_cast<double*>(offg + 2 * oi));
    }
    __syncthreads();

    // ---------------- phase 2: bilinear grid sample, group-sequential ------
    int hl = t & 15, wl = t >> 4;          // hh-fast: gather coalescing
    int shh = hh0 + hl, sww = ww0 + wl;
    const float* xg = x + (size_t)b * CIN * NPIX;

    int sh = t >> 4, sc = t & 15;          // store mapping (ww-fast)
    float* ob = out + (((size_t)b * CIN) * HOUT + (hh0 + sh)) * WOUT + (ww0 + sc);

    for (int g = 0; g < 4; ++g) {
        float2 off = soff[g][hl][wl];
        // transposed coords: ix (column) from hh, iy (row) from ww
        float ix = 2.0f * ((float)shh + 0.5f + off.x) - 0.5f;
        float iy = 2.0f * ((float)sww + 0.5f + off.y) - 0.5f;
        ix = fminf(fmaxf(ix, 0.0f), (float)(WIN - 1));
        iy = fminf(fmaxf(iy, 0.0f), (float)(HIN - 1));

        float x0f = floorf(ix), y0f = floorf(iy);
        float wx = ix - x0f, wy = iy - y0f;
        int x0 = (int)x0f, y0 = (int)y0f;
        int x1 = min(x0 + 1, WIN - 1);
        int y1 = min(y0 + 1, HIN - 1);

        float w00 = (1.0f - wx) * (1.0f - wy);
        float w01 = wx * (1.0f - wy);
        float w10 = (1.0f - wx) * wy;
        float w11 = wx * wy;

        int i00 = y0 * WIN + x0, i01 = y0 * WIN + x1;
        int i10 = y1 * WIN + x0, i11 = y1 * WIN + x1;

        const float* xgc = xg + (size_t)g * NPIX;   // channel c*4+g

        float v[16];
        // fast path: x0 even with real right neighbor -> aligned float2 loads
        bool fastp = ((x0 & 1) == 0) && (x1 == x0 + 1);
        if (fastp) {
            #pragma unroll
            for (int c = 0; c < 16; ++c) {
                const float* xc = xgc + (size_t)c * 4 * NPIX;
                float2 a = *reinterpret_cast<const float2*>(xc + i00);
                float2 d = *reinterpret_cast<const float2*>(xc + i10);
                v[c] = a.x * w00 + a.y * w01 + d.x * w10 + d.y * w11;
            }
        } else {
            #pragma unroll
            for (int c = 0; c < 16; ++c) {
                const float* xc = xgc + (size_t)c * 4 * NPIX;
                v[c] = xc[i00] * w00 + xc[i01] * w01
                     + xc[i10] * w10 + xc[i11] * w11;
            }
        }

        __syncthreads();   // previous group's sval reads complete
        #pragma unroll
        for (int c = 0; c < 16; ++c)
            sval[c][hl * 17 + wl] = v[c];
        __syncthreads();   // sval ready

        // coalesced nontemporal stores (don't evict x from cache)
        #pragma unroll
        for (int c = 0; c < 16; ++c)
            __builtin_nontemporal_store(sval[c][sh * 17 + sc],
                                        &ob[(size_t)(c * 4 + g) * NPIXO]);
    }
}

extern "C" void kernel_launch(void* const* d_in, const int* in_sizes, int n_in,
                              void* d_out, int out_size, void* d_ws, size_t ws_size,
                              hipStream_t stream) {
    const float* x     = (const float*)d_in[0];
    const float* w_off = (const float*)d_in[1];
    const float* b_off = (const float*)d_in[2];
    const float* w_sc  = (const float*)d_in[3];
    const float* b_sc  = (const float*)d_in[4];

    float* out  = (float*)d_out;
    float* offg = out + OUT0_SIZE;   // second return value, concatenated

    // 1024 blocks (16 batches x 64 tiles), XCD-pair-swizzled decode in-kernel
    k_fused<<<1024, 256, 0, stream>>>(x, w_off, b_off, w_sc, b_sc, out, offg);
}